// Round 2
// baseline (1132.659 us; speedup 1.0000x reference)
//
#include <hip/hip_runtime.h>
#include <hip/hip_bf16.h>
#include <math.h>

#define HH    512
#define NHEAD 8
#define DHEAD 64
#define BB    4096
#define NNB   8192
#define SS    16
#define KNB   16
#define GG    (BB + NNB)   // 12288

// ---------------------------------------------------------------------------
// Kernel 1: masked mean over S for span rows [0,B) and neighbor rows [B,G).
// One block (256 threads) per row; each thread owns one float2 column pair.
// ---------------------------------------------------------------------------
__global__ __launch_bounds__(256) void mean_kernel(
    const float* __restrict__ span_out, const float* __restrict__ nb_out,
    const int* __restrict__ span_mask, const int* __restrict__ nb_mask,
    float* __restrict__ mean)
{
    int row = blockIdx.x;
    const float* src; const int* msk;
    if (row < BB) { src = span_out + (size_t)row * SS * HH; msk = span_mask + (size_t)row * SS; }
    else          { int r = row - BB; src = nb_out + (size_t)r * SS * HH; msk = nb_mask + (size_t)r * SS; }

    __shared__ float keep[SS];
    if (threadIdx.x < SS) keep[threadIdx.x] = (msk[threadIdx.x] != 1) ? 1.0f : 0.0f;
    __syncthreads();

    float cnt = 0.0f;
#pragma unroll
    for (int s = 0; s < SS; s++) cnt += keep[s];
    float inv = 1.0f / cnt;   // mask[:,0] is always 0 -> cnt >= 1

    const float2* s2 = (const float2*)src;  // 256 float2 per (row,s)
    int t = threadIdx.x;
    float ax = 0.0f, ay = 0.0f;
#pragma unroll
    for (int s = 0; s < SS; s++) {
        float2 v = s2[s * (HH / 2) + t];
        float k = keep[s];
        ax += k * v.x;
        ay += k * v.y;
    }
    float2 o; o.x = ax * inv; o.y = ay * inv;
    ((float2*)mean)[(size_t)row * (HH / 2) + t] = o;
}

// ---------------------------------------------------------------------------
// Kernel 2: repack ws_W (HOP, HEAD, H, D) -> Wcat[hop][k][e*64+d], 2x(512x512)
// ---------------------------------------------------------------------------
__global__ __launch_bounds__(256) void repack_ws_kernel(
    const float* __restrict__ wsW, float* __restrict__ Wcat)
{
    int idx = blockIdx.x * 256 + threadIdx.x;        // < 2*512*512
    int hop = idx >> 18;
    int rem = idx & 262143;
    int k = rem >> 9;
    int nn = rem & 511;
    int e = nn >> 6, d = nn & 63;
    Wcat[idx] = wsW[(((size_t)hop * NHEAD + e) * HH + k) * DHEAD + d];
}

// ---------------------------------------------------------------------------
// Kernel 3: empty flags: empty[n] = all(graph_map[n,k] == -1)
// ---------------------------------------------------------------------------
__global__ __launch_bounds__(256) void empty_kernel(
    const int* __restrict__ gmap, int* __restrict__ empty)
{
    int n = blockIdx.x * 256 + threadIdx.x;
    if (n >= GG) return;
    int all_neg = 1;
#pragma unroll
    for (int k = 0; k < KNB; k++) all_neg &= (gmap[(size_t)n * KNB + k] == -1) ? 1 : 0;
    empty[n] = all_neg;
}

// ---------------------------------------------------------------------------
// Kernel 4: GEMM  Out = lrelu(A @ Wt + bias), fp32. A: MxK, Wt: KxN row-major.
// 64x64 block tile, 4x4 per thread, fp32 acc. M%64==0, N%64==0, K%32==0.
// ---------------------------------------------------------------------------
#define TBM 64
#define TBN 64
#define TBK 32
__global__ __launch_bounds__(256) void gemm_bias_lrelu(
    const float* __restrict__ A, const float* __restrict__ Wt,
    const float* __restrict__ bias, float* __restrict__ Out,
    int M, int N, int K)
{
    __shared__ float As[TBM][TBK + 1];
    __shared__ __align__(16) float Bs[TBK][TBN];
    int ntiles = N / TBN;
    int bx = blockIdx.x % ntiles;
    int by = blockIdx.x / ntiles;
    int tid = threadIdx.x;
    int tx = tid & 15, ty = tid >> 4;
    int rowA0 = by * TBM, colB0 = bx * TBN;
    float acc[4][4] = {{0.0f}};

    for (int k0 = 0; k0 < K; k0 += TBK) {
#pragma unroll
        for (int i = 0; i < 2; i++) {          // A tile: 64 rows x 8 float4
            int j = tid + i * 256;
            int r = j >> 3, cp = j & 7;
            float4 a4 = *(const float4*)(A + (size_t)(rowA0 + r) * K + k0 + cp * 4);
            As[r][cp * 4 + 0] = a4.x;
            As[r][cp * 4 + 1] = a4.y;
            As[r][cp * 4 + 2] = a4.z;
            As[r][cp * 4 + 3] = a4.w;
        }
#pragma unroll
        for (int i = 0; i < 2; i++) {          // B tile: 32 rows x 16 float4
            int j = tid + i * 256;
            int r = j >> 4, cp = j & 15;
            float4 b4 = *(const float4*)(Wt + (size_t)(k0 + r) * N + colB0 + cp * 4);
            *(float4*)&Bs[r][cp * 4] = b4;
        }
        __syncthreads();
#pragma unroll
        for (int kk = 0; kk < TBK; kk++) {
            const float4 b4 = *reinterpret_cast<const float4*>(&Bs[kk][tx * 4]);
            float bv[4] = {b4.x, b4.y, b4.z, b4.w};
#pragma unroll
            for (int i = 0; i < 4; i++) {
                float a = As[ty * 4 + i][kk];
#pragma unroll
                for (int j2 = 0; j2 < 4; j2++) acc[i][j2] += a * bv[j2];
            }
        }
        __syncthreads();
    }
#pragma unroll
    for (int i = 0; i < 4; i++) {
        int r = rowA0 + ty * 4 + i;
#pragma unroll
        for (int j2 = 0; j2 < 4; j2++) {
            int c = colB0 + tx * 4 + j2;
            float v = acc[i][j2] + bias[c];
            v = (v < 0.0f) ? 0.01f * v : v;
            Out[(size_t)r * N + c] = v;
        }
    }
}

// ---------------------------------------------------------------------------
// Kernel 5: GAT attention + per-head output matmul for one hop.
// One wave per (node n, head e); lane = d in [0,64). ch: G x 512 table.
// ---------------------------------------------------------------------------
__global__ __launch_bounds__(256) void attn_kernel(
    const float* __restrict__ ch, const int* __restrict__ gmap,
    const int* __restrict__ empty,
    const float* __restrict__ gatW,  // 8 x 128 x 64  (this hop)
    const float* __restrict__ gatB,  // 8 x 64        (this hop)
    float* __restrict__ out, int n_out)
{
    int wid = threadIdx.x >> 6;
    int lane = threadIdx.x & 63;
    int gid = blockIdx.x * 4 + wid;
    int n = gid >> 3, e = gid & 7;
    if (n >= n_out) return;

    size_t obase = (size_t)n * HH + e * DHEAD + lane;
    if (empty[n]) { out[obase] = 0.0f; return; }

    float node = ch[(size_t)n * HH + e * DHEAD + lane];

    float ctx[KNB], sc[KNB];
#pragma unroll
    for (int k = 0; k < KNB; k++) {
        int m = gmap[(size_t)n * KNB + k];
        int sm = (m < 0) ? 0 : m;
        float c = ch[(size_t)sm * HH + e * DHEAD + lane];
        ctx[k] = c;
        float p = node * c;
#pragma unroll
        for (int off = 32; off > 0; off >>= 1) p += __shfl_xor(p, off, 64);
        sc[k] = (m < 0) ? -1e9f : p;
    }

    float mx = -INFINITY;
#pragma unroll
    for (int k = 0; k < KNB; k++) mx = fmaxf(mx, sc[k]);
    float ssum = 0.0f; float at[KNB];
#pragma unroll
    for (int k = 0; k < KNB; k++) { at[k] = __expf(sc[k] - mx); ssum += at[k]; }
    float rs = 1.0f / ssum;
    float mixed = 0.0f;
#pragma unroll
    for (int k = 0; k < KNB; k++) mixed += at[k] * rs * ctx[k];

    // out[d'] = tanh( sum_c comb[c] * W[c][d'] + b[d'] ), comb = [mixed | node]
    const float* W = gatW + (size_t)e * 2 * DHEAD * DHEAD;
    float acc = gatB[e * DHEAD + lane];
#pragma unroll
    for (int c = 0; c < DHEAD; c++) {
        float bm = __shfl(mixed, c, 64);
        float bn = __shfl(node, c, 64);
        acc += bm * W[c * DHEAD + lane];
        acc += bn * W[(DHEAD + c) * DHEAD + lane];
    }
    out[obase] = tanhf(acc);
}

// ---------------------------------------------------------------------------
// Kernel 6: Af = [span_hidden | (empty ? b_hidden : c1)]
// ---------------------------------------------------------------------------
__global__ __launch_bounds__(256) void afinal_kernel(
    const float* __restrict__ span_hidden, const float* __restrict__ all_h,
    const float* __restrict__ c1, const int* __restrict__ empty,
    float* __restrict__ Af)
{
    int idx = blockIdx.x * 256 + threadIdx.x;    // < B*1024
    int n = idx >> 10, col = idx & 1023;
    float v;
    if (col < HH) v = span_hidden[(size_t)n * HH + col];
    else {
        int cc = col - HH;
        v = empty[n] ? all_h[(size_t)n * HH + cc] : c1[(size_t)n * HH + cc];
    }
    Af[idx] = v;
}

// ---------------------------------------------------------------------------
extern "C" void kernel_launch(void* const* d_in, const int* in_sizes, int n_in,
                              void* d_out, int out_size, void* d_ws, size_t ws_size,
                              hipStream_t stream)
{
    const float* span_hidden = (const float*)d_in[0];
    const float* span_output = (const float*)d_in[1];
    const float* nb_output   = (const float*)d_in[2];
    const int*   span_mask   = (const int*)d_in[3];
    const int*   nb_mask     = (const int*)d_in[4];
    const int*   graph_map   = (const int*)d_in[5];
    const float* proj_W = (const float*)d_in[6];
    const float* proj_b = (const float*)d_in[7];
    const float* ws_W   = (const float*)d_in[8];
    const float* ws_b   = (const float*)d_in[9];
    const float* gat_W  = (const float*)d_in[10];
    const float* gat_b  = (const float*)d_in[11];
    const float* ff_W   = (const float*)d_in[12];
    const float* ff_b   = (const float*)d_in[13];
    float* out = (float*)d_out;

    char* w = (char*)d_ws;
    size_t off = 0;
    const size_t SZ_GH = (size_t)GG * HH * sizeof(float);   // 25.2 MB
    // buf0: mean -> (after all_h GEMM) chbuf hop0 -> chbuf hop1 -> Af
    float* buf0  = (float*)(w + off); off += SZ_GH;
    float* all_h = (float*)(w + off); off += SZ_GH;         // b_hidden = rows [0,B)
    float* buf2  = (float*)(w + off); off += SZ_GH;         // cbuf hop0, then c1
    float* Wcat  = (float*)(w + off); off += (size_t)2 * HH * HH * sizeof(float);
    int*   empty = (int*)(w + off);   off += (size_t)GG * sizeof(int);
    (void)ws_size; (void)in_sizes; (void)n_in; (void)out_size;

    float* mean   = buf0;
    float* chbuf  = buf0;    // reused after mean is consumed
    float* cbuf   = buf2;
    float* c1     = buf2;    // reused: cbuf dead once hop1 GEMM has consumed it? NO —
    // hop1 GEMM reads cbuf and writes chbuf(buf0); c1 written by attn AFTER that,
    // reading only chbuf -> safe to overwrite cbuf rows [0,B) with c1.
    float* Af     = buf0;    // chbuf dead after hop1 attn; B*2H fits in G*H

    // 1. masked means for all G rows
    mean_kernel<<<GG, 256, 0, stream>>>(span_output, nb_output, span_mask, nb_mask, mean);
    // 2. repack ws weights, 3. empty flags
    repack_ws_kernel<<<(2 * HH * HH) / 256, 256, 0, stream>>>(ws_W, Wcat);
    empty_kernel<<<(GG + 255) / 256, 256, 0, stream>>>(graph_map, empty);
    // 4. all_h = lrelu(mean @ proj_W + proj_b)
    gemm_bias_lrelu<<<(GG / TBM) * (HH / TBN), 256, 0, stream>>>(
        mean, proj_W, proj_b, all_h, GG, HH, HH);
    // 5. hop 0: ch = lrelu(all_h @ Wcat0 + ws_b0)  [chbuf aliases mean: mean dead]
    gemm_bias_lrelu<<<(GG / TBM) * (HH / TBN), 256, 0, stream>>>(
        all_h, Wcat, ws_b, chbuf, GG, HH, HH);
    attn_kernel<<<(GG * NHEAD) / 4, 256, 0, stream>>>(
        chbuf, graph_map, empty, gat_W, gat_b, cbuf, GG);
    // 6. hop 1: ch = lrelu(c @ Wcat1 + ws_b1) over all G, attention over B
    gemm_bias_lrelu<<<(GG / TBM) * (HH / TBN), 256, 0, stream>>>(
        cbuf, Wcat + (size_t)HH * HH, ws_b + HH, chbuf, GG, HH, HH);
    attn_kernel<<<(BB * NHEAD) / 4, 256, 0, stream>>>(
        chbuf, graph_map, empty, gat_W + (size_t)NHEAD * 2 * DHEAD * DHEAD,
        gat_b + NHEAD * DHEAD, c1, BB);
    // 7. Af = [span_hidden | where(empty, b_hidden, c1)]   [Af aliases chbuf: dead]
    afinal_kernel<<<(BB * 2 * HH) / 256, 256, 0, stream>>>(
        span_hidden, all_h, c1, empty, Af);
    // 8. out = lrelu(Af @ ff_W + ff_b)
    gemm_bias_lrelu<<<(BB / TBM) * (HH / TBN), 256, 0, stream>>>(
        Af, ff_W, ff_b, out, BB, HH, 2 * HH);
}

// Round 3
// 904.220 us; speedup vs baseline: 1.2526x; 1.2526x over previous
//
#include <hip/hip_runtime.h>
#include <hip/hip_bf16.h>
#include <math.h>

#define HH    512
#define NHEAD 8
#define DHEAD 64
#define BB    4096
#define NNB   8192
#define SS    16
#define KNB   16
#define GG    (BB + NNB)   // 12288

typedef unsigned short ushort_t;
typedef __attribute__((ext_vector_type(8))) short short8;
typedef __attribute__((ext_vector_type(4))) float float4v;

// RNE float -> bf16 bits (inputs finite; no NaN handling needed)
__device__ __forceinline__ ushort_t f2bf(float f) {
    unsigned int u = __float_as_uint(f);
    unsigned int r = (u + 0x7fffu + ((u >> 16) & 1u)) >> 16;
    return (ushort_t)r;
}

// ---------------------------------------------------------------------------
// Kernel 1: masked mean over S. One block per row.
// ---------------------------------------------------------------------------
__global__ __launch_bounds__(256) void mean_kernel(
    const float* __restrict__ span_out, const float* __restrict__ nb_out,
    const int* __restrict__ span_mask, const int* __restrict__ nb_mask,
    float* __restrict__ mean)
{
    int row = blockIdx.x;
    const float* src; const int* msk;
    if (row < BB) { src = span_out + (size_t)row * SS * HH; msk = span_mask + (size_t)row * SS; }
    else          { int r = row - BB; src = nb_out + (size_t)r * SS * HH; msk = nb_mask + (size_t)r * SS; }

    __shared__ float keep[SS];
    if (threadIdx.x < SS) keep[threadIdx.x] = (msk[threadIdx.x] != 1) ? 1.0f : 0.0f;
    __syncthreads();

    float cnt = 0.0f;
#pragma unroll
    for (int s = 0; s < SS; s++) cnt += keep[s];
    float inv = 1.0f / cnt;

    const float2* s2 = (const float2*)src;
    int t = threadIdx.x;
    float ax = 0.0f, ay = 0.0f;
#pragma unroll
    for (int s = 0; s < SS; s++) {
        float2 v = s2[s * (HH / 2) + t];
        float k = keep[s];
        ax += k * v.x;
        ay += k * v.y;
    }
    float2 o; o.x = ax * inv; o.y = ay * inv;
    ((float2*)mean)[(size_t)row * (HH / 2) + t] = o;
}

// ---------------------------------------------------------------------------
// Kernel 2: repack ws_W (HOP,HEAD,H,D) -> WcatT bf16 [hop][n=e*64+d][k]
// ---------------------------------------------------------------------------
__global__ __launch_bounds__(256) void repack_ws_kernel(
    const float* __restrict__ wsW, ushort_t* __restrict__ WcatT)
{
    int idx = blockIdx.x * 256 + threadIdx.x;        // < 2*512*512
    int hop = idx >> 18;
    int rem = idx & 262143;
    int n = rem >> 9;          // e*64+d
    int k = rem & 511;
    int e = n >> 6, d = n & 63;
    WcatT[idx] = f2bf(wsW[(((size_t)hop * NHEAD + e) * HH + k) * DHEAD + d]);
}

// ---------------------------------------------------------------------------
// Kernel 2b: tiled transpose+convert: out_bf[n*K+k] = bf16(in[k*N+n])
// grid = (K/32)*(N/32) blocks of 256
// ---------------------------------------------------------------------------
__global__ __launch_bounds__(256) void tconv_kernel(
    const float* __restrict__ in, ushort_t* __restrict__ out, int K, int N)
{
    __shared__ float t[32][33];
    int kb = blockIdx.x % (K / 32);
    int nb = blockIdx.x / (K / 32);
    int x = threadIdx.x & 31, y = threadIdx.x >> 5;   // y in 0..7
#pragma unroll
    for (int i = 0; i < 4; i++)
        t[y + 8 * i][x] = in[(size_t)(kb * 32 + y + 8 * i) * N + nb * 32 + x];
    __syncthreads();
#pragma unroll
    for (int i = 0; i < 4; i++)
        out[(size_t)(nb * 32 + y + 8 * i) * K + kb * 32 + x] = f2bf(t[x][y + 8 * i]);
}

// ---------------------------------------------------------------------------
// Kernel 3: empty flags
// ---------------------------------------------------------------------------
__global__ __launch_bounds__(256) void empty_kernel(
    const int* __restrict__ gmap, int* __restrict__ empty)
{
    int n = blockIdx.x * 256 + threadIdx.x;
    if (n >= GG) return;
    int all_neg = 1;
#pragma unroll
    for (int k = 0; k < KNB; k++) all_neg &= (gmap[(size_t)n * KNB + k] == -1) ? 1 : 0;
    empty[n] = all_neg;
}

// ---------------------------------------------------------------------------
// Kernel 4: MFMA GEMM  Out = lrelu(A @ W + bias), A fp32 MxK row-major,
// Wt bf16 [N][K] (pre-transposed), Out fp32 MxN. fp32 accumulate.
// BM=BN=128, BK=32; 4 waves, each computes 64x64 via 4x4 mfma_f32_16x16x32_bf16.
// M%128==0, N%128==0, K%32==0.
// ---------------------------------------------------------------------------
#define BM 128
#define BN 128
#define BK 32
__global__ __launch_bounds__(256) void gemm_mfma(
    const float* __restrict__ A, const ushort_t* __restrict__ Wt,
    const float* __restrict__ bias, float* __restrict__ Out,
    int M, int N, int K)
{
    __shared__ __align__(16) ushort_t As[BM * BK];   // [m][k]
    __shared__ __align__(16) ushort_t Bs[BN * BK];   // [n][k]
    int nb = N / BN;
    int by = blockIdx.x / nb, bx = blockIdx.x % nb;
    int row0 = by * BM, col0 = bx * BN;
    int tid = threadIdx.x;
    int lane = tid & 63, w = tid >> 6;
    int wr = (w >> 1) * 64, wc = (w & 1) * 64;
    int l15 = lane & 15, quad = lane >> 4;

    // staging assignments
    int sm = tid >> 1;                 // 0..127 (row for A, row-of-Wt for B)
    int skh = (tid & 1) * 16;          // k half

    float4v acc[4][4] = {};

    for (int k0 = 0; k0 < K; k0 += BK) {
        // stage A: 128x32 fp32 -> bf16
        {
            const float* src = A + (size_t)(row0 + sm) * K + k0 + skh;
            short8 pack[2];
#pragma unroll
            for (int h = 0; h < 2; h++) {
#pragma unroll
                for (int u = 0; u < 2; u++) {
                    float4v v = *(const float4v*)(src + h * 8 + u * 4);
                    pack[h][u * 4 + 0] = (short)f2bf(v.x);
                    pack[h][u * 4 + 1] = (short)f2bf(v.y);
                    pack[h][u * 4 + 2] = (short)f2bf(v.z);
                    pack[h][u * 4 + 3] = (short)f2bf(v.w);
                }
            }
            *(short8*)&As[sm * BK + skh]     = pack[0];
            *(short8*)&As[sm * BK + skh + 8] = pack[1];
        }
        // stage B: 128x32 bf16 copy
        {
            const ushort_t* src = Wt + (size_t)(col0 + sm) * K + k0 + skh;
            *(short8*)&Bs[sm * BK + skh]     = *(const short8*)src;
            *(short8*)&Bs[sm * BK + skh + 8] = *(const short8*)(src + 8);
        }
        __syncthreads();

        short8 af[4], bf[4];
#pragma unroll
        for (int i = 0; i < 4; i++)
            af[i] = *(const short8*)&As[(wr + i * 16 + l15) * BK + quad * 8];
#pragma unroll
        for (int j = 0; j < 4; j++)
            bf[j] = *(const short8*)&Bs[(wc + j * 16 + l15) * BK + quad * 8];
#pragma unroll
        for (int i = 0; i < 4; i++)
#pragma unroll
            for (int j = 0; j < 4; j++)
                acc[i][j] = __builtin_amdgcn_mfma_f32_16x16x32_bf16(
                    af[i], bf[j], acc[i][j], 0, 0, 0);
        __syncthreads();
    }

#pragma unroll
    for (int i = 0; i < 4; i++) {
#pragma unroll
        for (int r = 0; r < 4; r++) {
            int rr = row0 + wr + i * 16 + quad * 4 + r;
#pragma unroll
            for (int j = 0; j < 4; j++) {
                int cc = col0 + wc + j * 16 + l15;
                float v = acc[i][j][r] + bias[cc];
                v = (v < 0.0f) ? 0.01f * v : v;
                Out[(size_t)rr * N + cc] = v;
            }
        }
    }
}

// ---------------------------------------------------------------------------
// Kernel 5: GAT attention (unchanged from round 2)
// ---------------------------------------------------------------------------
__global__ __launch_bounds__(256) void attn_kernel(
    const float* __restrict__ ch, const int* __restrict__ gmap,
    const int* __restrict__ empty,
    const float* __restrict__ gatW, const float* __restrict__ gatB,
    float* __restrict__ out, int n_out)
{
    int wid = threadIdx.x >> 6;
    int lane = threadIdx.x & 63;
    int gid = blockIdx.x * 4 + wid;
    int n = gid >> 3, e = gid & 7;
    if (n >= n_out) return;

    size_t obase = (size_t)n * HH + e * DHEAD + lane;
    if (empty[n]) { out[obase] = 0.0f; return; }

    float node = ch[(size_t)n * HH + e * DHEAD + lane];

    float ctx[KNB], sc[KNB];
#pragma unroll
    for (int k = 0; k < KNB; k++) {
        int m = gmap[(size_t)n * KNB + k];
        int smi = (m < 0) ? 0 : m;
        float c = ch[(size_t)smi * HH + e * DHEAD + lane];
        ctx[k] = c;
        float p = node * c;
#pragma unroll
        for (int off = 32; off > 0; off >>= 1) p += __shfl_xor(p, off, 64);
        sc[k] = (m < 0) ? -1e9f : p;
    }

    float mx = -INFINITY;
#pragma unroll
    for (int k = 0; k < KNB; k++) mx = fmaxf(mx, sc[k]);
    float ssum = 0.0f; float at[KNB];
#pragma unroll
    for (int k = 0; k < KNB; k++) { at[k] = __expf(sc[k] - mx); ssum += at[k]; }
    float rs = 1.0f / ssum;
    float mixed = 0.0f;
#pragma unroll
    for (int k = 0; k < KNB; k++) mixed += at[k] * rs * ctx[k];

    const float* W = gatW + (size_t)e * 2 * DHEAD * DHEAD;
    float acc = gatB[e * DHEAD + lane];
#pragma unroll
    for (int c = 0; c < DHEAD; c++) {
        float bm = __shfl(mixed, c, 64);
        float bn = __shfl(node, c, 64);
        acc += bm * W[c * DHEAD + lane];
        acc += bn * W[(DHEAD + c) * DHEAD + lane];
    }
    out[obase] = tanhf(acc);
}

// ---------------------------------------------------------------------------
// Kernel 6: Af = [span_hidden | (empty ? b_hidden : c1)]
// ---------------------------------------------------------------------------
__global__ __launch_bounds__(256) void afinal_kernel(
    const float* __restrict__ span_hidden, const float* __restrict__ all_h,
    const float* __restrict__ c1, const int* __restrict__ empty,
    float* __restrict__ Af)
{
    int idx = blockIdx.x * 256 + threadIdx.x;
    int n = idx >> 10, col = idx & 1023;
    float v;
    if (col < HH) v = span_hidden[(size_t)n * HH + col];
    else {
        int cc = col - HH;
        v = empty[n] ? all_h[(size_t)n * HH + cc] : c1[(size_t)n * HH + cc];
    }
    Af[idx] = v;
}

// ---------------------------------------------------------------------------
extern "C" void kernel_launch(void* const* d_in, const int* in_sizes, int n_in,
                              void* d_out, int out_size, void* d_ws, size_t ws_size,
                              hipStream_t stream)
{
    const float* span_hidden = (const float*)d_in[0];
    const float* span_output = (const float*)d_in[1];
    const float* nb_output   = (const float*)d_in[2];
    const int*   span_mask   = (const int*)d_in[3];
    const int*   nb_mask     = (const int*)d_in[4];
    const int*   graph_map   = (const int*)d_in[5];
    const float* proj_W = (const float*)d_in[6];
    const float* proj_b = (const float*)d_in[7];
    const float* ws_W   = (const float*)d_in[8];
    const float* ws_b   = (const float*)d_in[9];
    const float* gat_W  = (const float*)d_in[10];
    const float* gat_b  = (const float*)d_in[11];
    const float* ff_W   = (const float*)d_in[12];
    const float* ff_b   = (const float*)d_in[13];
    float* out = (float*)d_out;

    char* w = (char*)d_ws;
    size_t off = 0;
    const size_t SZ_GH = (size_t)GG * HH * sizeof(float);   // 25.17 MB
    float*    buf0  = (float*)(w + off);    off += SZ_GH;   // mean -> chbuf -> Af
    float*    all_h = (float*)(w + off);    off += SZ_GH;
    float*    buf2  = (float*)(w + off);    off += SZ_GH;   // cbuf -> c1
    ushort_t* WcatT = (ushort_t*)(w + off); off += (size_t)2 * HH * HH * sizeof(ushort_t);
    ushort_t* wslot = (ushort_t*)(w + off); off += (size_t)2 * HH * HH * sizeof(ushort_t); // projT then ffT (1MB)
    int*      empty = (int*)(w + off);      off += (size_t)GG * sizeof(int);
    (void)ws_size; (void)in_sizes; (void)n_in; (void)out_size;

    float* mean  = buf0;
    float* chbuf = buf0;
    float* cbuf  = buf2;
    float* c1    = buf2;
    float* Af    = buf0;
    ushort_t* projT = wslot;   // 512x512 bf16, used by GEMM1
    ushort_t* ffT   = wslot;   // 512x1024 bf16, written after GEMM1, used by GEMM4

    // 1. masked means
    mean_kernel<<<GG, 256, 0, stream>>>(span_output, nb_output, span_mask, nb_mask, mean);
    // 2. weight prep + empty flags
    repack_ws_kernel<<<(2 * HH * HH) / 256, 256, 0, stream>>>(ws_W, WcatT);
    tconv_kernel<<<(HH / 32) * (HH / 32), 256, 0, stream>>>(proj_W, projT, HH, HH);
    empty_kernel<<<(GG + 255) / 256, 256, 0, stream>>>(graph_map, empty);
    // 3. all_h = lrelu(mean @ proj_W + proj_b)
    gemm_mfma<<<(GG / BM) * (HH / BN), 256, 0, stream>>>(
        mean, projT, proj_b, all_h, GG, HH, HH);
    // projT dead -> build ffT in the same slot
    tconv_kernel<<<((2 * HH) / 32) * (HH / 32), 256, 0, stream>>>(ff_W, ffT, 2 * HH, HH);
    // 4. hop 0
    gemm_mfma<<<(GG / BM) * (HH / BN), 256, 0, stream>>>(
        all_h, WcatT, ws_b, chbuf, GG, HH, HH);
    attn_kernel<<<(GG * NHEAD) / 4, 256, 0, stream>>>(
        chbuf, graph_map, empty, gat_W, gat_b, cbuf, GG);
    // 5. hop 1
    gemm_mfma<<<(GG / BM) * (HH / BN), 256, 0, stream>>>(
        cbuf, WcatT + (size_t)HH * HH, ws_b + HH, chbuf, GG, HH, HH);
    attn_kernel<<<(BB * NHEAD) / 4, 256, 0, stream>>>(
        chbuf, graph_map, empty, gat_W + (size_t)NHEAD * 2 * DHEAD * DHEAD,
        gat_b + NHEAD * DHEAD, c1, BB);
    // 6. Af = [span_hidden | where(empty, b_hidden, c1)]
    afinal_kernel<<<(BB * 2 * HH) / 256, 256, 0, stream>>>(
        span_hidden, all_h, c1, empty, Af);
    // 7. out = lrelu(Af @ ff_W + ff_b)
    gemm_mfma<<<(BB / BM) * (HH / BN), 256, 0, stream>>>(
        Af, ffT, ff_b, out, BB, HH, 2 * HH);
}

// Round 4
// 695.100 us; speedup vs baseline: 1.6295x; 1.3008x over previous
//
#include <hip/hip_runtime.h>
#include <hip/hip_bf16.h>
#include <math.h>

#define HH    512
#define NHEAD 8
#define DHEAD 64
#define BB    4096
#define NNB   8192
#define SS    16
#define KNB   16
#define GG    (BB + NNB)   // 12288

typedef unsigned short ushort_t;
typedef __attribute__((ext_vector_type(8))) short short8;
typedef __attribute__((ext_vector_type(4))) float float4v;

// RNE float -> bf16 bits (inputs finite)
__device__ __forceinline__ ushort_t f2bf(float f) {
    unsigned int u = __float_as_uint(f);
    unsigned int r = (u + 0x7fffu + ((u >> 16) & 1u)) >> 16;
    return (ushort_t)r;
}

// ---------------------------------------------------------------------------
// Kernel 1: masked mean over S. One block per row.
// ---------------------------------------------------------------------------
__global__ __launch_bounds__(256) void mean_kernel(
    const float* __restrict__ span_out, const float* __restrict__ nb_out,
    const int* __restrict__ span_mask, const int* __restrict__ nb_mask,
    float* __restrict__ mean)
{
    int row = blockIdx.x;
    const float* src; const int* msk;
    if (row < BB) { src = span_out + (size_t)row * SS * HH; msk = span_mask + (size_t)row * SS; }
    else          { int r = row - BB; src = nb_out + (size_t)r * SS * HH; msk = nb_mask + (size_t)r * SS; }

    __shared__ float keep[SS];
    if (threadIdx.x < SS) keep[threadIdx.x] = (msk[threadIdx.x] != 1) ? 1.0f : 0.0f;
    __syncthreads();

    float cnt = 0.0f;
#pragma unroll
    for (int s = 0; s < SS; s++) cnt += keep[s];
    float inv = 1.0f / cnt;

    const float2* s2 = (const float2*)src;
    int t = threadIdx.x;
    float ax = 0.0f, ay = 0.0f;
#pragma unroll
    for (int s = 0; s < SS; s++) {
        float2 v = s2[s * (HH / 2) + t];
        float k = keep[s];
        ax += k * v.x;
        ay += k * v.y;
    }
    float2 o; o.x = ax * inv; o.y = ay * inv;
    ((float2*)mean)[(size_t)row * (HH / 2) + t] = o;
}

// ---------------------------------------------------------------------------
// Kernel 2: repack ws_W (HOP,HEAD,H,D) -> WcatT bf16 [hop][n=e*64+d][k]
// ---------------------------------------------------------------------------
__global__ __launch_bounds__(256) void repack_ws_kernel(
    const float* __restrict__ wsW, ushort_t* __restrict__ WcatT)
{
    int idx = blockIdx.x * 256 + threadIdx.x;        // < 2*512*512
    int hop = idx >> 18;
    int rem = idx & 262143;
    int n = rem >> 9;          // e*64+d
    int k = rem & 511;
    int e = n >> 6, d = n & 63;
    WcatT[idx] = f2bf(wsW[(((size_t)hop * NHEAD + e) * HH + k) * DHEAD + d]);
}

// ---------------------------------------------------------------------------
// Kernel 2b: tiled transpose+convert: out_bf[n*K+k] = bf16(in[k*N+n])
// ---------------------------------------------------------------------------
__global__ __launch_bounds__(256) void tconv_kernel(
    const float* __restrict__ in, ushort_t* __restrict__ out, int K, int N)
{
    __shared__ float t[32][33];
    int kb = blockIdx.x % (K / 32);
    int nb = blockIdx.x / (K / 32);
    int x = threadIdx.x & 31, y = threadIdx.x >> 5;   // y in 0..7
#pragma unroll
    for (int i = 0; i < 4; i++)
        t[y + 8 * i][x] = in[(size_t)(kb * 32 + y + 8 * i) * N + nb * 32 + x];
    __syncthreads();
#pragma unroll
    for (int i = 0; i < 4; i++)
        out[(size_t)(nb * 32 + y + 8 * i) * K + kb * 32 + x] = f2bf(t[x][y + 8 * i]);
}

// ---------------------------------------------------------------------------
// Kernel 2c: repack gat_W [hop][e][c=128][d=64] fp32 -> WgT [hop][e][d][c] bf16
// ---------------------------------------------------------------------------
__global__ __launch_bounds__(256) void repack_gat_kernel(
    const float* __restrict__ gatW, ushort_t* __restrict__ WgT)
{
    int idx = blockIdx.x * 256 + threadIdx.x;   // < 2*8*64*128 = 131072
    int he = idx >> 13;            // hop*8+e
    int d  = (idx >> 7) & 63;
    int c  = idx & 127;
    WgT[idx] = f2bf(gatW[((size_t)he * 128 + c) * 64 + d]);
}

// ---------------------------------------------------------------------------
// Kernel 3: empty flags
// ---------------------------------------------------------------------------
__global__ __launch_bounds__(256) void empty_kernel(
    const int* __restrict__ gmap, int* __restrict__ empty)
{
    int n = blockIdx.x * 256 + threadIdx.x;
    if (n >= GG) return;
    int all_neg = 1;
#pragma unroll
    for (int k = 0; k < KNB; k++) all_neg &= (gmap[(size_t)n * KNB + k] == -1) ? 1 : 0;
    empty[n] = all_neg;
}

// ---------------------------------------------------------------------------
// Kernel 4: MFMA GEMM  Out = lrelu(A @ W + bias), A fp32 MxK row-major,
// Wt bf16 [N][K]. BM=BN=128, BK=32; 4 waves, 64x64 each, fp32 acc.
// ---------------------------------------------------------------------------
#define BM 128
#define BN 128
#define BK 32
__global__ __launch_bounds__(256) void gemm_mfma(
    const float* __restrict__ A, const ushort_t* __restrict__ Wt,
    const float* __restrict__ bias, float* __restrict__ Out,
    int M, int N, int K)
{
    __shared__ __align__(16) ushort_t As[BM * BK];   // [m][k]
    __shared__ __align__(16) ushort_t Bs[BN * BK];   // [n][k]
    int nb = N / BN;
    int by = blockIdx.x / nb, bx = blockIdx.x % nb;
    int row0 = by * BM, col0 = bx * BN;
    int tid = threadIdx.x;
    int lane = tid & 63, w = tid >> 6;
    int wr = (w >> 1) * 64, wc = (w & 1) * 64;
    int l15 = lane & 15, quad = lane >> 4;

    int sm = tid >> 1;
    int skh = (tid & 1) * 16;

    float4v acc[4][4] = {};

    for (int k0 = 0; k0 < K; k0 += BK) {
        {
            const float* src = A + (size_t)(row0 + sm) * K + k0 + skh;
            short8 pack[2];
#pragma unroll
            for (int h = 0; h < 2; h++) {
#pragma unroll
                for (int u = 0; u < 2; u++) {
                    float4v v = *(const float4v*)(src + h * 8 + u * 4);
                    pack[h][u * 4 + 0] = (short)f2bf(v.x);
                    pack[h][u * 4 + 1] = (short)f2bf(v.y);
                    pack[h][u * 4 + 2] = (short)f2bf(v.z);
                    pack[h][u * 4 + 3] = (short)f2bf(v.w);
                }
            }
            *(short8*)&As[sm * BK + skh]     = pack[0];
            *(short8*)&As[sm * BK + skh + 8] = pack[1];
        }
        {
            const ushort_t* src = Wt + (size_t)(col0 + sm) * K + k0 + skh;
            *(short8*)&Bs[sm * BK + skh]     = *(const short8*)src;
            *(short8*)&Bs[sm * BK + skh + 8] = *(const short8*)(src + 8);
        }
        __syncthreads();

        short8 af[4], bf[4];
#pragma unroll
        for (int i = 0; i < 4; i++)
            af[i] = *(const short8*)&As[(wr + i * 16 + l15) * BK + quad * 8];
#pragma unroll
        for (int j = 0; j < 4; j++)
            bf[j] = *(const short8*)&Bs[(wc + j * 16 + l15) * BK + quad * 8];
#pragma unroll
        for (int i = 0; i < 4; i++)
#pragma unroll
            for (int j = 0; j < 4; j++)
                acc[i][j] = __builtin_amdgcn_mfma_f32_16x16x32_bf16(
                    af[i], bf[j], acc[i][j], 0, 0, 0);
        __syncthreads();
    }

#pragma unroll
    for (int i = 0; i < 4; i++) {
#pragma unroll
        for (int r = 0; r < 4; r++) {
            int rr = row0 + wr + i * 16 + quad * 4 + r;
#pragma unroll
            for (int j = 0; j < 4; j++) {
                int cc = col0 + wc + j * 16 + l15;
                float v = acc[i][j][r] + bias[cc];
                v = (v < 0.0f) ? 0.01f * v : v;
                Out[(size_t)rr * N + cc] = v;
            }
        }
    }
}

// ---------------------------------------------------------------------------
// Kernel 5a: attention mixing. One wave per (n,e); lane = (k = lane>>2,
// j = lane&3). Scores via 10 shuffles, Sum_k attn*ctx via per-wave LDS
// transpose. Writes comb = [mixed | node] bf16 (G x 1024).
// ---------------------------------------------------------------------------
__global__ __launch_bounds__(256) void attn_mix_kernel(
    const float* __restrict__ ch, const int* __restrict__ gmap,
    ushort_t* __restrict__ comb, int n_out)
{
    __shared__ float sred[4][16 * 68];   // per-wave 16 rows, stride 68 (pad)
    int wid = threadIdx.x >> 6, lane = threadIdx.x & 63;
    int gid = blockIdx.x * 4 + wid;
    int n = gid >> 3, e = gid & 7;
    if (n >= n_out) return;
    int j = lane & 3, k = lane >> 2;

    int m = gmap[(size_t)n * KNB + k];
    int sm = (m < 0) ? 0 : m;

    const float4v* ctxp = (const float4v*)(ch + (size_t)sm * HH + e * DHEAD + j * 16);
    const float4v* nodp = (const float4v*)(ch + (size_t)n  * HH + e * DHEAD + j * 16);
    float4v c0 = ctxp[0], c1 = ctxp[1], c2 = ctxp[2], c3 = ctxp[3];
    float4v n0 = nodp[0], n1 = nodp[1], n2 = nodp[2], n3 = nodp[3];

    float p = 0.0f;
#pragma unroll
    for (int i = 0; i < 4; i++) p += c0[i] * n0[i];
#pragma unroll
    for (int i = 0; i < 4; i++) p += c1[i] * n1[i];
#pragma unroll
    for (int i = 0; i < 4; i++) p += c2[i] * n2[i];
#pragma unroll
    for (int i = 0; i < 4; i++) p += c3[i] * n3[i];
    p += __shfl_xor(p, 1, 64);
    p += __shfl_xor(p, 2, 64);

    float sc = (m < 0) ? -1e9f : p;
    float mx = sc;
#pragma unroll
    for (int off = 4; off <= 32; off <<= 1) mx = fmaxf(mx, __shfl_xor(mx, off, 64));
    float ex = __expf(sc - mx);
    float ssum = ex;
#pragma unroll
    for (int off = 4; off <= 32; off <<= 1) ssum += __shfl_xor(ssum, off, 64);
    float at = ex / ssum;

    float* red = &sred[wid][k * 68 + j * 16];
    ((float4v*)red)[0] = c0 * at;
    ((float4v*)red)[1] = c1 * at;
    ((float4v*)red)[2] = c2 * at;
    ((float4v*)red)[3] = c3 * at;

    // lane d sums the 16 neighbor contributions for its output dim
    const float* base = &sred[wid][lane];
    float acc = 0.0f;
#pragma unroll
    for (int kk = 0; kk < KNB; kk++) acc += base[kk * 68];

    size_t cb = (size_t)n * (NHEAD * 128) + e * 128 + lane;
    comb[cb]      = f2bf(acc);
    comb[cb + 64] = f2bf(ch[(size_t)n * HH + e * DHEAD + lane]);
}

// ---------------------------------------------------------------------------
// Kernel 5b: per-head GAT GEMM: dst[r][e*64+d'] = (empty[r] ? 0 :
//   tanh( sum_c comb[r][e*128+c] * WgT[e][d'][c] + gatB[e][d'] ) )
// grid = (Mrows/128) * 8 heads; K=128 single stage.
// ---------------------------------------------------------------------------
#define GAK 136
__global__ __launch_bounds__(256) void gat_gemm_kernel(
    const ushort_t* __restrict__ comb, const ushort_t* __restrict__ WgT,
    const float* __restrict__ gatB, const int* __restrict__ empty,
    float* __restrict__ dst, int Mrows)
{
    __shared__ __align__(16) ushort_t As[128 * GAK];
    __shared__ __align__(16) ushort_t Bs[64 * GAK];
    int e = blockIdx.x & 7;
    int row0 = (blockIdx.x >> 3) * 128;
    int tid = threadIdx.x;

#pragma unroll
    for (int i = 0; i < 8; i++) {
        int f = tid + i * 256;            // 0..2047
        int r = f >> 4, c8 = f & 15;
        *(short8*)&As[r * GAK + c8 * 8] =
            *(const short8*)(comb + (size_t)(row0 + r) * 1024 + e * 128 + c8 * 8);
    }
#pragma unroll
    for (int i = 0; i < 4; i++) {
        int f = tid + i * 256;            // 0..1023
        int r = f >> 4, c8 = f & 15;
        *(short8*)&Bs[r * GAK + c8 * 8] =
            *(const short8*)(WgT + (size_t)e * 8192 + r * 128 + c8 * 8);
    }
    __syncthreads();

    int lane = tid & 63, w = tid >> 6;
    int l15 = lane & 15, quad = lane >> 4;
    int wr = w * 32;
    float4v acc[2][4] = {};
#pragma unroll
    for (int kq = 0; kq < 4; kq++) {
        short8 af[2], bf[4];
#pragma unroll
        for (int mi = 0; mi < 2; mi++)
            af[mi] = *(const short8*)&As[(wr + mi * 16 + l15) * GAK + kq * 32 + quad * 8];
#pragma unroll
        for (int nj = 0; nj < 4; nj++)
            bf[nj] = *(const short8*)&Bs[(nj * 16 + l15) * GAK + kq * 32 + quad * 8];
#pragma unroll
        for (int mi = 0; mi < 2; mi++)
#pragma unroll
            for (int nj = 0; nj < 4; nj++)
                acc[mi][nj] = __builtin_amdgcn_mfma_f32_16x16x32_bf16(
                    af[mi], bf[nj], acc[mi][nj], 0, 0, 0);
    }

#pragma unroll
    for (int mi = 0; mi < 2; mi++) {
#pragma unroll
        for (int r = 0; r < 4; r++) {
            int rr = row0 + wr + mi * 16 + quad * 4 + r;
            int emp = empty[rr];
#pragma unroll
            for (int nj = 0; nj < 4; nj++) {
                int cc = nj * 16 + l15;
                float v = tanhf(acc[mi][nj][r] + gatB[e * 64 + cc]);
                dst[(size_t)rr * HH + e * 64 + cc] = emp ? 0.0f : v;
            }
        }
    }
}

// ---------------------------------------------------------------------------
// Kernel 6: Af = [span_hidden | (empty ? b_hidden : c1)]
// ---------------------------------------------------------------------------
__global__ __launch_bounds__(256) void afinal_kernel(
    const float* __restrict__ span_hidden, const float* __restrict__ all_h,
    const float* __restrict__ c1, const int* __restrict__ empty,
    float* __restrict__ Af)
{
    int idx = blockIdx.x * 256 + threadIdx.x;
    int n = idx >> 10, col = idx & 1023;
    float v;
    if (col < HH) v = span_hidden[(size_t)n * HH + col];
    else {
        int cc = col - HH;
        v = empty[n] ? all_h[(size_t)n * HH + cc] : c1[(size_t)n * HH + cc];
    }
    Af[idx] = v;
}

// ---------------------------------------------------------------------------
extern "C" void kernel_launch(void* const* d_in, const int* in_sizes, int n_in,
                              void* d_out, int out_size, void* d_ws, size_t ws_size,
                              hipStream_t stream)
{
    const float* span_hidden = (const float*)d_in[0];
    const float* span_output = (const float*)d_in[1];
    const float* nb_output   = (const float*)d_in[2];
    const int*   span_mask   = (const int*)d_in[3];
    const int*   nb_mask     = (const int*)d_in[4];
    const int*   graph_map   = (const int*)d_in[5];
    const float* proj_W = (const float*)d_in[6];
    const float* proj_b = (const float*)d_in[7];
    const float* ws_W   = (const float*)d_in[8];
    const float* ws_b   = (const float*)d_in[9];
    const float* gat_W  = (const float*)d_in[10];
    const float* gat_b  = (const float*)d_in[11];
    const float* ff_W   = (const float*)d_in[12];
    const float* ff_b   = (const float*)d_in[13];
    float* out = (float*)d_out;

    char* w = (char*)d_ws;
    size_t off = 0;
    const size_t SZ_GH = (size_t)GG * HH * sizeof(float);   // 25.17 MB
    float*    buf0  = (float*)(w + off);    off += SZ_GH;   // mean -> chbuf -> Af
    float*    all_h = (float*)(w + off);    off += SZ_GH;
    float*    buf2  = (float*)(w + off);    off += SZ_GH;   // cbuf -> c1
    ushort_t* comb  = (ushort_t*)(w + off); off += (size_t)GG * 1024 * sizeof(ushort_t); // 25.17 MB
    ushort_t* WcatT = (ushort_t*)(w + off); off += (size_t)2 * HH * HH * sizeof(ushort_t);
    ushort_t* wslot = (ushort_t*)(w + off); off += (size_t)2 * HH * HH * sizeof(ushort_t);
    ushort_t* WgT   = (ushort_t*)(w + off); off += (size_t)2 * NHEAD * 64 * 128 * sizeof(ushort_t);
    int*      empty = (int*)(w + off);      off += (size_t)GG * sizeof(int);
    (void)ws_size; (void)in_sizes; (void)n_in; (void)out_size;

    float* mean  = buf0;
    float* chbuf = buf0;
    float* cbuf  = buf2;
    float* c1    = buf2;
    float* Af    = buf0;
    ushort_t* projT = wslot;
    ushort_t* ffT   = wslot;

    // 1. masked means
    mean_kernel<<<GG, 256, 0, stream>>>(span_output, nb_output, span_mask, nb_mask, mean);
    // 2. weight prep + empty flags
    repack_ws_kernel<<<(2 * HH * HH) / 256, 256, 0, stream>>>(ws_W, WcatT);
    tconv_kernel<<<(HH / 32) * (HH / 32), 256, 0, stream>>>(proj_W, projT, HH, HH);
    repack_gat_kernel<<<(2 * NHEAD * 64 * 128) / 256, 256, 0, stream>>>(gat_W, WgT);
    empty_kernel<<<(GG + 255) / 256, 256, 0, stream>>>(graph_map, empty);
    // 3. all_h = lrelu(mean @ proj_W + proj_b)
    gemm_mfma<<<(GG / BM) * (HH / BN), 256, 0, stream>>>(
        mean, projT, proj_b, all_h, GG, HH, HH);
    tconv_kernel<<<((2 * HH) / 32) * (HH / 32), 256, 0, stream>>>(ff_W, ffT, 2 * HH, HH);
    // 4. hop 0
    gemm_mfma<<<(GG / BM) * (HH / BN), 256, 0, stream>>>(
        all_h, WcatT, ws_b, chbuf, GG, HH, HH);
    attn_mix_kernel<<<(GG * NHEAD) / 4, 256, 0, stream>>>(chbuf, graph_map, comb, GG);
    gat_gemm_kernel<<<(GG / 128) * 8, 256, 0, stream>>>(
        comb, WgT, gat_b, empty, cbuf, GG);
    // 5. hop 1
    gemm_mfma<<<(GG / BM) * (HH / BN), 256, 0, stream>>>(
        cbuf, WcatT + (size_t)HH * HH, ws_b + HH, chbuf, GG, HH, HH);
    attn_mix_kernel<<<(BB * NHEAD) / 4, 256, 0, stream>>>(chbuf, graph_map, comb, BB);
    gat_gemm_kernel<<<(BB / 128) * 8, 256, 0, stream>>>(
        comb, WgT + (size_t)NHEAD * 64 * 128, gat_b + NHEAD * DHEAD, empty, c1, BB);
    // 6. Af = [span_hidden | where(empty, b_hidden, c1)]
    afinal_kernel<<<(BB * 2 * HH) / 256, 256, 0, stream>>>(
        span_hidden, all_h, c1, empty, Af);
    // 7. out = lrelu(Af @ ff_W + ff_b)
    gemm_mfma<<<(BB / BM) * (HH / BN), 256, 0, stream>>>(
        Af, ffT, ff_b, out, BB, HH, 2 * HH);
}